// Round 1
// baseline (1853.892 us; speedup 1.0000x reference)
//
#include <hip/hip_runtime.h>
#include <hip/hip_bf16.h>

#define Bdim 64
#define Gdim 1024
#define Ddim 256
#define Fdim 1024

typedef short s8v __attribute__((ext_vector_type(8)));
typedef float f4v __attribute__((ext_vector_type(4)));

__device__ __forceinline__ float bf2f(short s){
  return __uint_as_float(((unsigned)(unsigned short)s) << 16);
}
__device__ __forceinline__ short f2bf(float f){
  unsigned u = __float_as_uint(f);
  u = u + 0x7fffu + ((u >> 16) & 1u);   // RNE
  return (short)(u >> 16);
}
__device__ __forceinline__ s8v ld8(const short* p){ return *(const s8v*)p; }

#define MFMA_BF16(a,b,c) __builtin_amdgcn_mfma_f32_16x16x32_bf16((a),(b),(c),0,0,0)

// ------------------------------------------------------------ dtype detection
__global__ __launch_bounds__(256) void detect_dtype(const unsigned* __restrict__ x,
                                                    int* __restrict__ flag){
  __shared__ int cnt[256];
  int c = 0;
  #pragma unroll
  for (int j=0;j<4;j++){
    unsigned u = x[threadIdx.x*4 + j];
    int e = (u >> 7) & 0xFF;
    c += (e >= 100 && e <= 140) ? 1 : 0;
  }
  cnt[threadIdx.x] = c;
  __syncthreads();
  if (threadIdx.x == 0){
    int s = 0;
    for (int i=0;i<256;i++) s += cnt[i];
    flag[0] = (s >= 512) ? 0 : 1;   // 0 = bf16 inputs, 1 = fp32 inputs
  }
}

// ------------------------------------------------------------ diagnostic
__global__ void diag_ws(void* o, float v, const int* __restrict__ flag){
  if (threadIdx.x == 0){
    if (flag[0]){ ((float*)o)[0] = v; ((float*)o)[16777216] = v; }
    else        { ((short*)o)[0] = f2bf(v); ((short*)o)[16777216] = f2bf(v); }
  }
}

// ------------------------------------------------------------ input -> fp32 h
__global__ __launch_bounds__(256) void cast_in(const void* __restrict__ x,
                                               float* __restrict__ h32,
                                               const int* __restrict__ flag){
  size_t i = ((size_t)blockIdx.x * 256 + threadIdx.x) * 8;
  if (flag[0]){
    const float* xf = (const float*)x;
    #pragma unroll
    for (int j=0;j<8;j++) h32[i+j] = xf[i+j];
  } else {
    s8v v = ld8((const short*)x + i);
    #pragma unroll
    for (int j=0;j<8;j++) h32[i+j] = bf2f(v[j]);
  }
}

// ------------------------------------------------------------ weight transpose -> bf16, stackable dst
__global__ __launch_bounds__(256) void transpose_w(const void* __restrict__ src,
                                                   short* __restrict__ dh, int R, int C,
                                                   const int* __restrict__ flag,
                                                   int dzs, int dbase){
  __shared__ short th[32][33];
  int fl = flag[0];
  size_t soff = (size_t)blockIdx.z * R * C;
  size_t doff = (size_t)dbase + (size_t)blockIdx.z * dzs;
  int c0 = blockIdx.x*32, r0 = blockIdx.y*32;
  int tx = threadIdx.x, ty = threadIdx.y;
  #pragma unroll
  for (int i=ty;i<32;i+=8){
    size_t idx = soff + (size_t)(r0+i)*C + (c0+tx);
    float w = fl ? ((const float*)src)[idx] : bf2f(((const short*)src)[idx]);
    th[i][tx] = f2bf(w);
  }
  __syncthreads();
  #pragma unroll
  for (int i=ty;i<32;i+=8)
    dh[doff + (size_t)(c0+i)*R + (r0+tx)] = th[tx][i];
}

// ------------------------------------------------------------ biases -> fp32
// [0..511]=bo(2x256)  [512..2559]=bf1(2x1024)  [2560..3071]=bf2(2x256)
__global__ __launch_bounds__(256) void bias_prep(const void* __restrict__ bo,
                                                 const void* __restrict__ bf1,
                                                 const void* __restrict__ bf2,
                                                 float* __restrict__ biasf,
                                                 const int* __restrict__ flag){
  int fl = flag[0];
  int i = blockIdx.x*256 + threadIdx.x;
  const void* src; int idx;
  if (i < 512){ src = bo; idx = i; }
  else if (i < 2560){ src = bf1; idx = i - 512; }
  else { src = bf2; idx = i - 2560; }
  biasf[i] = fl ? ((const float*)src)[idx] : bf2f(((const short*)src)[idx]);
}

// ------------------------------------------------------------ GEMM template
// AM: 0 = A bf16; 1 = A fp32 -> hi only; 2 = A fp32 -> hi+lo split (2 MFMA)
// EPI: 0 = bf16 store; 1 = relu(acc+bias) bf16 store;
//      4 = h32[idx] += acc + bias; 5 = fused QKV routing (Q,K row-major; V transposed)
template<int AM, int EPI>
__global__ __launch_bounds__(256) void gemm_t(
    const void* __restrict__ Ap, const short* __restrict__ Bh,
    const float* __restrict__ bias, float* __restrict__ hout,
    short* __restrict__ outb, int N, int K, int lda, int ldb, int Mrows)
{
  constexpr int AT = (AM==2) ? 2 : 1;
  __shared__ short As[AT*128*40];
  __shared__ short Bs[128*40];
  short* Asl = As + 128*40;
  const int tid = threadIdx.x;
  const int lane = tid & 63, wave = tid >> 6;
  const int quad = lane >> 4, l16 = lane & 15;
  const int m0 = blockIdx.x * 128, n0 = blockIdx.y * 128;
  const int wr = wave >> 1, wc = wave & 1;
  f4v acc[4][4];
  #pragma unroll
  for (int i=0;i<4;i++)
    #pragma unroll
    for (int j=0;j<4;j++) acc[i][j] = f4v{0.f,0.f,0.f,0.f};

  for (int k0 = 0; k0 < K; k0 += 32){
    __syncthreads();
    #pragma unroll
    for (int i=0;i<2;i++){
      int v = tid + i*256;
      int r = v >> 2, c8 = (v & 3) * 8;
      if (AM == 0){
        *(s8v*)(&As[r*40 + c8]) = ld8((const short*)Ap + (size_t)(m0 + r)*lda + k0 + c8);
      } else {
        const float* af = (const float*)Ap + (size_t)(m0 + r)*lda + k0 + c8;
        float4 f0 = *(const float4*)af;
        float4 f1 = *(const float4*)(af + 4);
        float fv[8] = {f0.x,f0.y,f0.z,f0.w,f1.x,f1.y,f1.z,f1.w};
        s8v hi, lo;
        #pragma unroll
        for (int j=0;j<8;j++) hi[j] = f2bf(fv[j]);
        *(s8v*)(&As[r*40 + c8]) = hi;
        if (AM == 2){
          #pragma unroll
          for (int j=0;j<8;j++) lo[j] = f2bf(fv[j] - bf2f(hi[j]));
          *(s8v*)(&Asl[r*40 + c8]) = lo;
        }
      }
      *(s8v*)(&Bs[r*40 + c8]) = ld8(Bh + (size_t)(n0 + r)*ldb + k0 + c8);
    }
    __syncthreads();
    s8v ah[4], al[4], bh[4];
    #pragma unroll
    for (int t=0;t<4;t++){
      ah[t] = ld8(&As[(wr*64 + t*16 + l16)*40 + quad*8]);
      bh[t] = ld8(&Bs[(wc*64 + t*16 + l16)*40 + quad*8]);
      if (AM == 2) al[t] = ld8(&Asl[(wr*64 + t*16 + l16)*40 + quad*8]);
    }
    #pragma unroll
    for (int ti=0;ti<4;ti++)
      #pragma unroll
      for (int tj=0;tj<4;tj++){
        acc[ti][tj] = MFMA_BF16(ah[ti], bh[tj], acc[ti][tj]);
        if (AM == 2) acc[ti][tj] = MFMA_BF16(al[ti], bh[tj], acc[ti][tj]);
      }
  }
  #pragma unroll
  for (int tj=0;tj<4;tj++){
    int col = n0 + wc*64 + tj*16 + l16;
    float bs = (EPI==1 || EPI==4) ? (bias ? bias[col] : 0.f) : 0.f;
    #pragma unroll
    for (int ti=0;ti<4;ti++){
      #pragma unroll
      for (int r=0;r<4;r++){
        int row = m0 + wr*64 + ti*16 + quad*4 + r;
        float v = acc[ti][tj][r];
        if (EPI == 0){
          outb[(size_t)row * N + col] = f2bf(v);
        } else if (EPI == 1){
          v += bs; v = v > 0.f ? v : 0.f;
          outb[(size_t)row * N + col] = f2bf(v);
        } else if (EPI == 4){
          size_t idx = (size_t)row * N + col;
          hout[idx] += v + bs;
        } else {  // EPI == 5: fused QKV
          int sec = col >> 8, c = col & 255;
          if (sec == 0)      outb[(size_t)row*256 + c] = f2bf(v);
          else if (sec == 1) (outb + (size_t)Mrows*256)[(size_t)row*256 + c] = f2bf(v);
          else {
            int bb = row >> 10, g = row & 1023;
            (outb + (size_t)2*Mrows*256)[(size_t)bb*262144 + (size_t)c*1024 + g] = f2bf(v);
          }
        }
      }
    }
  }
}

// ------------------------------------------------------------ flash attention (barrier-free)
// grid (16*CB) 1D. Q,K bf16 [CB*1024 x 256]; Vt bf16 [CB][256][1024];
// H bf16 [CB*1024 x 256]. K and V^T MFMA B-fragments are read DIRECTLY from
// global (K/V per batch = 512 KB each -> L2-resident; LDS staging was pure
// overhead + 4 barriers/kt). Only LDS left: per-wave P transpose buffer ->
// zero __syncthreads in the whole kernel; waves fully independent.
// XCD swizzle: all 16 q-tile blocks of a batch land on the same XCD so its
// K/V stay in that XCD's 4 MiB L2.
__global__ __launch_bounds__(256) void flash_attn(
    const short* __restrict__ Q, const short* __restrict__ Kmat,
    const short* __restrict__ Vt, const int* __restrict__ mask,
    short* __restrict__ H)
{
  __shared__ short Ps[4*16*72];   // per-wave P [16 qrows][64 keys], stride 72
  const int tid = threadIdx.x;
  const int lane = tid & 63, wave = tid >> 6;
  const int quad = lane >> 4, l16 = lane & 15;
  // XCD-aware swizzle (HW round-robins linear block id % 8 across XCDs):
  // batch b -> XCD b%8; bijective since gridDim.x = 16*CB, CB % 8 == 0.
  const int bid = blockIdx.x;
  const int slot = bid >> 3;
  const int b  = (bid & 7) + ((slot >> 4) << 3);
  const int qt = slot & 15;
  const short* Qb  = Q    + (size_t)b*Gdim*Ddim;
  const short* Kb  = Kmat + (size_t)b*Gdim*Ddim;
  const short* Vtb = Vt   + (size_t)b*Ddim*Gdim;
  const int qrow = qt*64 + wave*16 + l16;
  s8v qf[8];
  #pragma unroll
  for (int s=0;s<8;s++) qf[s] = ld8(Qb + (size_t)qrow*Ddim + s*32 + quad*8);
  // per-lane fragment base pointers (row = l16 within tile, + quad sub-col)
  const short* Krow = Kb  + (size_t)l16*Ddim + quad*8;   // + (k0+tj*16)*256 + st*32
  const short* Vrow = Vtb + (size_t)l16*Gdim + quad*8;   // + tt*16*1024 + k0 + st*32
  float mrow[4], lrow[4];
  #pragma unroll
  for (int r=0;r<4;r++){ mrow[r] = -1e9f; lrow[r] = 0.f; }
  f4v O[16];
  #pragma unroll
  for (int t=0;t<16;t++) O[t] = f4v{0.f,0.f,0.f,0.f};
  short* Pw = Ps + wave*16*72;

  for (int kt=0; kt<16; kt++){
    const int k0 = kt*64;
    // mask loads issued early to hide L2 latency under QK^T
    int mk[4];
    #pragma unroll
    for (int tj=0;tj<4;tj++) mk[tj] = mask[b*Gdim + k0 + tj*16 + l16];
    // ---- QK^T: B fragments straight from global K (L2), 2-deep pipelined
    f4v sc[4];
    #pragma unroll
    for (int tj=0;tj<4;tj++) sc[tj] = f4v{0.f,0.f,0.f,0.f};
    s8v kb[2][4];
    #pragma unroll
    for (int tj=0;tj<4;tj++)
      kb[0][tj] = ld8(Krow + (size_t)(k0 + tj*16)*Ddim);
    #pragma unroll
    for (int st=0; st<8; st++){
      if (st < 7){
        #pragma unroll
        for (int tj=0;tj<4;tj++)
          kb[(st+1)&1][tj] = ld8(Krow + (size_t)(k0 + tj*16)*Ddim + (st+1)*32);
      }
      #pragma unroll
      for (int tj=0;tj<4;tj++)
        sc[tj] = MFMA_BF16(qf[st], kb[st&1][tj], sc[tj]);
    }
    // ---- online softmax (unchanged semantics: masked -> -30, stays in
    //      denominator, zeroed in numerator)
    float al[4], pvv[4][4];
    bool need = false;
    #pragma unroll
    for (int r=0;r<4;r++){
      float mx = -1e9f;
      #pragma unroll
      for (int tj=0;tj<4;tj++){
        float v = sc[tj][r] * 0.0625f;
        if (mk[tj]) v = -30.f;
        sc[tj][r] = v;
        mx = fmaxf(mx, v);
      }
      #pragma unroll
      for (int mm=1; mm<16; mm<<=1) mx = fmaxf(mx, __shfl_xor(mx, mm));
      float mn = fmaxf(mrow[r], mx);
      al[r] = __expf(mrow[r] - mn);
      need |= (al[r] < 1.f);
      mrow[r] = mn;
      float ps = 0.f;
      #pragma unroll
      for (int tj=0;tj<4;tj++){
        float e = __expf(sc[tj][r] - mn);
        ps += e;
        pvv[tj][r] = mk[tj] ? 0.f : e;
      }
      #pragma unroll
      for (int mm=1; mm<16; mm<<=1) ps += __shfl_xor(ps, mm);
      lrow[r] = lrow[r]*al[r] + ps;
    }
    if (__any(need)){
      #pragma unroll
      for (int t=0;t<16;t++)
        #pragma unroll
        for (int r=0;r<4;r++) O[t][r] *= al[r];
    }
    // ---- P transpose through wave-private LDS (intra-wave only: lgkmcnt,
    //      no __syncthreads; DS pipe is in-order per wave so the next
    //      iteration's writes cannot bypass these reads)
    #pragma unroll
    for (int tj=0;tj<4;tj++)
      #pragma unroll
      for (int r=0;r<4;r++)
        Pw[(quad*4 + r)*72 + tj*16 + l16] = f2bf(pvv[tj][r]);
    asm volatile("s_waitcnt lgkmcnt(0)" ::: "memory");
    __builtin_amdgcn_sched_barrier(0);
    s8v pa0 = ld8(&Pw[l16*72 + quad*8]);
    s8v pa1 = ld8(&Pw[l16*72 + 32 + quad*8]);
    // ---- PV: B fragments straight from global V^T (already [d][k] layout)
    #pragma unroll
    for (int tt=0; tt<16; tt++){
      s8v vb0 = ld8(Vrow + (size_t)tt*16384 + k0);
      s8v vb1 = ld8(Vrow + (size_t)tt*16384 + k0 + 32);
      O[tt] = MFMA_BF16(pa0, vb0, O[tt]);
      O[tt] = MFMA_BF16(pa1, vb1, O[tt]);
    }
  }
  #pragma unroll
  for (int t=0;t<16;t++){
    #pragma unroll
    for (int r=0;r<4;r++){
      int row = qt*64 + wave*16 + quad*4 + r;
      int col = t*16 + l16;
      float dn = fmaxf(lrow[r], 1e-30f);
      H[((size_t)b*Gdim + row)*Ddim + col] = f2bf(O[t][r] / dn);
    }
  }
}

// ------------------------------------------------------------ mean + output
__global__ __launch_bounds__(256) void mean_partial(const float* __restrict__ h32,
                                                    float* __restrict__ part){
  int b = blockIdx.x, c = blockIdx.y, d = threadIdx.x;
  float s = 0.f;
  for (int g = c*64; g < c*64 + 64; g++)
    s += h32[((size_t)b*Gdim + g)*Ddim + d];
  part[(b*16 + c)*Ddim + d] = s;
}
__global__ __launch_bounds__(256) void mean_final_dyn(const float* __restrict__ part,
                                                      void* __restrict__ out,
                                                      const int* __restrict__ flag){
  int i = blockIdx.x*256 + threadIdx.x;
  int b = i >> 8, d = i & 255;
  float s = 0.f;
  #pragma unroll
  for (int c=0;c<16;c++) s += part[(b*16 + c)*Ddim + d];
  s *= (1.f/1024.f);
  if (flag[0]) ((float*)out)[16777216 + i] = s;
  else         ((short*)out)[16777216 + i] = f2bf(s);
}
__global__ __launch_bounds__(256) void store_h(const float* __restrict__ h32,
                                               void* __restrict__ out,
                                               const int* __restrict__ flag){
  size_t i = (size_t)blockIdx.x*256 + threadIdx.x;
  if (flag[0]) ((float*)out)[i] = h32[i];
  else         ((short*)out)[i] = f2bf(h32[i]);
}

// ------------------------------------------------------------ launch
extern "C" void kernel_launch(void* const* d_in, const int* in_sizes, int n_in,
                              void* d_out, int out_size, void* d_ws, size_t ws_size,
                              hipStream_t stream)
{
  const void* xs  = d_in[0];
  const int*  mask= (const int*)d_in[1];
  const void* Wq  = d_in[2];
  const void* Wk  = d_in[3];
  const void* Wv  = d_in[4];
  const void* Wo  = d_in[5];
  const void* bo  = d_in[6];
  const void* Wf1 = d_in[7];
  const void* bf1 = d_in[8];
  const void* Wf2 = d_in[9];
  const void* bf2 = d_in[10];

  // weights: Wqkv(768K) + Wo(256K) + Wf1(1M) + Wf2(1M) + biasf(12K)
  const size_t W_ALL = 786432 + 262144 + 1048576 + 1048576 + 12288;  // 3,158,016
  const size_t BASE  = 256 + 67108864;                               // flag + h32
  int CB;
  if      (ws_size >= BASE + 134217728ull + W_ALL) CB = 64;   // 204.5 MB
  else if (ws_size >= BASE +  67108864ull + W_ALL) CB = 32;   // 137.4 MB (proven reachable)
  else if (ws_size >= BASE +  33554432ull + W_ALL) CB = 16;
  else CB = 0;

  char* p = (char*)d_ws;
  int* flag = (int*)p; p += 256;
  detect_dtype<<<1, 256, 0, stream>>>((const unsigned*)xs, flag);
  if (CB == 0){
    diag_ws<<<1, 64, 0, stream>>>(d_out, 2000.f + (float)(ws_size >> 20), flag);
    return;
  }
  const int M = CB * 1024, nch = 64 / CB;
  float* h32 = (float*)p; p += 67108864;
  char* arena = p;        p += (size_t)CB * 2097152;
  short* WqkvT = (short*)p; p += 786432;
  short* WoT   = (short*)p; p += 262144;
  short* Wf1T  = (short*)p; p += 1048576;
  short* Wf2T  = (short*)p; p += 1048576;
  float* biasf = (float*)p; p += 12288;
  float* part  = (float*)arena;          // arena dead by mean time

  short* Qc  = (short*)arena;
  short* Kc  = Qc + (size_t)M*256;
  short* Vtc = Qc + (size_t)2*M*256;
  short* Hc  = Qc + (size_t)3*M*256;
  short* Tc  = Qc;                       // FFN intermediate spans whole arena

  cast_in<<<8192, 256, 0, stream>>>(xs, h32, flag);
  dim3 tb(32,8);
  transpose_w<<<dim3(8,8,2),  tb, 0, stream>>>(Wq,  WqkvT, 256, 256,  flag, 196608, 0);
  transpose_w<<<dim3(8,8,2),  tb, 0, stream>>>(Wk,  WqkvT, 256, 256,  flag, 196608, 65536);
  transpose_w<<<dim3(8,8,2),  tb, 0, stream>>>(Wv,  WqkvT, 256, 256,  flag, 196608, 131072);
  transpose_w<<<dim3(8,8,2),  tb, 0, stream>>>(Wo,  WoT,   256, 256,  flag, 65536, 0);
  transpose_w<<<dim3(32,8,2), tb, 0, stream>>>(Wf1, Wf1T,  256, 1024, flag, 262144, 0);
  transpose_w<<<dim3(8,32,2), tb, 0, stream>>>(Wf2, Wf2T,  1024, 256, flag, 262144, 0);
  bias_prep<<<12, 256, 0, stream>>>(bo, bf1, bf2, biasf, flag);

  for (int c=0; c<nch; c++){
    float* hc = h32 + (size_t)c*M*256;
    const int* mc = mask + (size_t)c*M;
    for (int l=0; l<2; l++){
      // fused QKV: A = h fp32 (hi), B = stacked [768][256]
      gemm_t<1,5><<<dim3(M/128,6), 256, 0, stream>>>(hc, WqkvT + l*196608, nullptr,
                                                     nullptr, Qc, 768, 256, 256, 256, M);
      flash_attn<<<dim3(16*CB), 256, 0, stream>>>(Qc, Kc, Vtc, mc, Hc);
      // O-proj: h32 += Hc*Wo + bo
      gemm_t<0,4><<<dim3(M/128,2), 256, 0, stream>>>(Hc, WoT + l*65536, biasf + l*256,
                                                     hc, nullptr, 256, 256, 256, 256, M);
      // FFN1: T = relu(h*Wf1 + b), A split
      gemm_t<2,1><<<dim3(M/128,8), 256, 0, stream>>>(hc, Wf1T + l*262144, biasf + 512 + l*1024,
                                                     nullptr, Tc, 1024, 256, 256, 256, M);
      // FFN2: h32 += T*Wf2 + b
      gemm_t<0,4><<<dim3(M/128,2), 256, 0, stream>>>(Tc, Wf2T + l*262144, biasf + 2560 + l*256,
                                                     hc, nullptr, 256, 1024, 1024, 1024, M);
    }
  }
  mean_partial<<<dim3(64,16), 256, 0, stream>>>(h32, part);
  store_h<<<65536, 256, 0, stream>>>(h32, d_out, flag);
  mean_final_dyn<<<64, 256, 0, stream>>>(part, d_out, flag);
}

// Round 2
// 1349.143 us; speedup vs baseline: 1.3741x; 1.3741x over previous
//
#include <hip/hip_runtime.h>
#include <hip/hip_bf16.h>

#define Bdim 64
#define Gdim 1024
#define Ddim 256
#define Fdim 1024

typedef short s8v __attribute__((ext_vector_type(8)));
typedef float f4v __attribute__((ext_vector_type(4)));

__device__ __forceinline__ float bf2f(short s){
  return __uint_as_float(((unsigned)(unsigned short)s) << 16);
}
__device__ __forceinline__ short f2bf(float f){
  unsigned u = __float_as_uint(f);
  u = u + 0x7fffu + ((u >> 16) & 1u);   // RNE
  return (short)(u >> 16);
}
__device__ __forceinline__ s8v ld8(const short* p){ return *(const s8v*)p; }

#define MFMA_BF16(a,b,c) __builtin_amdgcn_mfma_f32_16x16x32_bf16((a),(b),(c),0,0,0)

// async 16B global->LDS (linear dest; swizzle done on the SOURCE address)
#define GLDS16(gp, lp) __builtin_amdgcn_global_load_lds( \
    (const __attribute__((address_space(1))) void*)(gp), \
    (__attribute__((address_space(3))) void*)(lp), 16, 0, 0)

// ------------------------------------------------------------ dtype detection
__global__ __launch_bounds__(256) void detect_dtype(const unsigned* __restrict__ x,
                                                    int* __restrict__ flag){
  __shared__ int cnt[256];
  int c = 0;
  #pragma unroll
  for (int j=0;j<4;j++){
    unsigned u = x[threadIdx.x*4 + j];
    int e = (u >> 7) & 0xFF;
    c += (e >= 100 && e <= 140) ? 1 : 0;
  }
  cnt[threadIdx.x] = c;
  __syncthreads();
  if (threadIdx.x == 0){
    int s = 0;
    for (int i=0;i<256;i++) s += cnt[i];
    flag[0] = (s >= 512) ? 0 : 1;   // 0 = bf16 inputs, 1 = fp32 inputs
  }
}

// ------------------------------------------------------------ diagnostic
__global__ void diag_ws(void* o, float v, const int* __restrict__ flag){
  if (threadIdx.x == 0){
    if (flag[0]){ ((float*)o)[0] = v; ((float*)o)[16777216] = v; }
    else        { ((short*)o)[0] = f2bf(v); ((short*)o)[16777216] = f2bf(v); }
  }
}

// ------------------------------------------------------------ input -> fp32 h
__global__ __launch_bounds__(256) void cast_in(const void* __restrict__ x,
                                               float* __restrict__ h32,
                                               const int* __restrict__ flag){
  size_t i = ((size_t)blockIdx.x * 256 + threadIdx.x) * 8;
  if (flag[0]){
    const float* xf = (const float*)x;
    #pragma unroll
    for (int j=0;j<8;j++) h32[i+j] = xf[i+j];
  } else {
    s8v v = ld8((const short*)x + i);
    #pragma unroll
    for (int j=0;j<8;j++) h32[i+j] = bf2f(v[j]);
  }
}

// ------------------------------------------------------------ weight transpose -> bf16, stackable dst
__global__ __launch_bounds__(256) void transpose_w(const void* __restrict__ src,
                                                   short* __restrict__ dh, int R, int C,
                                                   const int* __restrict__ flag,
                                                   int dzs, int dbase){
  __shared__ short th[32][33];
  int fl = flag[0];
  size_t soff = (size_t)blockIdx.z * R * C;
  size_t doff = (size_t)dbase + (size_t)blockIdx.z * dzs;
  int c0 = blockIdx.x*32, r0 = blockIdx.y*32;
  int tx = threadIdx.x, ty = threadIdx.y;
  #pragma unroll
  for (int i=ty;i<32;i+=8){
    size_t idx = soff + (size_t)(r0+i)*C + (c0+tx);
    float w = fl ? ((const float*)src)[idx] : bf2f(((const short*)src)[idx]);
    th[i][tx] = f2bf(w);
  }
  __syncthreads();
  #pragma unroll
  for (int i=ty;i<32;i+=8)
    dh[doff + (size_t)(c0+i)*R + (r0+tx)] = th[tx][i];
}

// ------------------------------------------------------------ biases -> fp32
// [0..511]=bo(2x256)  [512..2559]=bf1(2x1024)  [2560..3071]=bf2(2x256)
__global__ __launch_bounds__(256) void bias_prep(const void* __restrict__ bo,
                                                 const void* __restrict__ bf1,
                                                 const void* __restrict__ bf2,
                                                 float* __restrict__ biasf,
                                                 const int* __restrict__ flag){
  int fl = flag[0];
  int i = blockIdx.x*256 + threadIdx.x;
  const void* src; int idx;
  if (i < 512){ src = bo; idx = i; }
  else if (i < 2560){ src = bf1; idx = i - 512; }
  else { src = bf2; idx = i - 2560; }
  biasf[i] = fl ? ((const float*)src)[idx] : bf2f(((const short*)src)[idx]);
}

// ------------------------------------------------------------ GEMM template
// AM: 0 = A bf16; 1 = A fp32 -> hi only; 2 = A fp32 -> hi+lo split (2 MFMA)
// EPI: 0 = bf16 store; 1 = relu(acc+bias) bf16 store;
//      4 = h32[idx] += acc + bias; 5 = fused QKV routing (Q,K row-major; V transposed)
template<int AM, int EPI>
__global__ __launch_bounds__(256) void gemm_t(
    const void* __restrict__ Ap, const short* __restrict__ Bh,
    const float* __restrict__ bias, float* __restrict__ hout,
    short* __restrict__ outb, int N, int K, int lda, int ldb, int Mrows)
{
  constexpr int AT = (AM==2) ? 2 : 1;
  __shared__ short As[AT*128*40];
  __shared__ short Bs[128*40];
  short* Asl = As + 128*40;
  const int tid = threadIdx.x;
  const int lane = tid & 63, wave = tid >> 6;
  const int quad = lane >> 4, l16 = lane & 15;
  const int m0 = blockIdx.x * 128, n0 = blockIdx.y * 128;
  const int wr = wave >> 1, wc = wave & 1;
  f4v acc[4][4];
  #pragma unroll
  for (int i=0;i<4;i++)
    #pragma unroll
    for (int j=0;j<4;j++) acc[i][j] = f4v{0.f,0.f,0.f,0.f};

  for (int k0 = 0; k0 < K; k0 += 32){
    __syncthreads();
    #pragma unroll
    for (int i=0;i<2;i++){
      int v = tid + i*256;
      int r = v >> 2, c8 = (v & 3) * 8;
      if (AM == 0){
        *(s8v*)(&As[r*40 + c8]) = ld8((const short*)Ap + (size_t)(m0 + r)*lda + k0 + c8);
      } else {
        const float* af = (const float*)Ap + (size_t)(m0 + r)*lda + k0 + c8;
        float4 f0 = *(const float4*)af;
        float4 f1 = *(const float4*)(af + 4);
        float fv[8] = {f0.x,f0.y,f0.z,f0.w,f1.x,f1.y,f1.z,f1.w};
        s8v hi, lo;
        #pragma unroll
        for (int j=0;j<8;j++) hi[j] = f2bf(fv[j]);
        *(s8v*)(&As[r*40 + c8]) = hi;
        if (AM == 2){
          #pragma unroll
          for (int j=0;j<8;j++) lo[j] = f2bf(fv[j] - bf2f(hi[j]));
          *(s8v*)(&Asl[r*40 + c8]) = lo;
        }
      }
      *(s8v*)(&Bs[r*40 + c8]) = ld8(Bh + (size_t)(n0 + r)*ldb + k0 + c8);
    }
    __syncthreads();
    s8v ah[4], al[4], bh[4];
    #pragma unroll
    for (int t=0;t<4;t++){
      ah[t] = ld8(&As[(wr*64 + t*16 + l16)*40 + quad*8]);
      bh[t] = ld8(&Bs[(wc*64 + t*16 + l16)*40 + quad*8]);
      if (AM == 2) al[t] = ld8(&Asl[(wr*64 + t*16 + l16)*40 + quad*8]);
    }
    #pragma unroll
    for (int ti=0;ti<4;ti++)
      #pragma unroll
      for (int tj=0;tj<4;tj++){
        acc[ti][tj] = MFMA_BF16(ah[ti], bh[tj], acc[ti][tj]);
        if (AM == 2) acc[ti][tj] = MFMA_BF16(al[ti], bh[tj], acc[ti][tj]);
      }
  }
  #pragma unroll
  for (int tj=0;tj<4;tj++){
    int col = n0 + wc*64 + tj*16 + l16;
    float bs = (EPI==1 || EPI==4) ? (bias ? bias[col] : 0.f) : 0.f;
    #pragma unroll
    for (int ti=0;ti<4;ti++){
      #pragma unroll
      for (int r=0;r<4;r++){
        int row = m0 + wr*64 + ti*16 + quad*4 + r;
        float v = acc[ti][tj][r];
        if (EPI == 0){
          outb[(size_t)row * N + col] = f2bf(v);
        } else if (EPI == 1){
          v += bs; v = v > 0.f ? v : 0.f;
          outb[(size_t)row * N + col] = f2bf(v);
        } else if (EPI == 4){
          size_t idx = (size_t)row * N + col;
          hout[idx] += v + bs;
        } else {  // EPI == 5: fused QKV
          int sec = col >> 8, c = col & 255;
          if (sec == 0)      outb[(size_t)row*256 + c] = f2bf(v);
          else if (sec == 1) (outb + (size_t)Mrows*256)[(size_t)row*256 + c] = f2bf(v);
          else {
            int bb = row >> 10, g = row & 1023;
            (outb + (size_t)2*Mrows*256)[(size_t)bb*262144 + (size_t)c*1024 + g] = f2bf(v);
          }
        }
      }
    }
  }
}

// ------------------------------------------------------------ flash attention v3
// 4 waves x 32 q-rows = 128 rows/block; 8 blocks/batch; grid 8*CB = 1 block/CU.
// K,V double-buffered in LDS via async global_load_lds (linear dest,
// XOR-pre-swizzled SOURCE, same XOR on ds_read -> conflict-free b128 reads).
// One __syncthreads per kt; stages issued at top of kt so the whole compute
// phase (~2500 cyc) covers load latency. 32 rows/wave -> each K/V fragment
// read feeds 2 MFMAs (MFMA-bound regime).
__global__ __launch_bounds__(256, 1) void flash_attn(
    const short* __restrict__ Q, const short* __restrict__ Kmat,
    const short* __restrict__ Vt, const int* __restrict__ mask,
    short* __restrict__ H)
{
  __shared__ short Ks[2][64*256];   // 64 KiB: K tile [64 keys][256 d], src-swizzled
  __shared__ short Vs[2][256*64];   // 64 KiB: V^T tile [256 d][64 keys], src-swizzled
  __shared__ short Ps[4][32*72];    // 18 KiB: per-wave P [32 qrows][64 keys]
  const int tid = threadIdx.x;
  const int lane = tid & 63, wave = tid >> 6;
  const int quad = lane >> 4, l16 = lane & 15;
  // batch -> XCD pinning: all 8 q-tile blocks of batch b share XCD b&7.
  const int bid = blockIdx.x;
  const int b  = (bid & 7) + ((bid >> 6) << 3);
  const int qt = (bid >> 3) & 7;
  const short* Qb  = Q    + (size_t)b*Gdim*Ddim;
  const short* Kb  = Kmat + (size_t)b*Gdim*Ddim;
  const short* Vtb = Vt   + (size_t)b*Ddim*Gdim;
  const int qbase = qt*128 + wave*32;

  auto stage = [&](int buf, int k0){
    #pragma unroll
    for (int i=0;i<8;i++){            // K tile: 32 KiB, 16B/thread x 8
      int idx = i*256 + tid;
      int r = idx >> 5, g = idx & 31;
      const short* gp = Kb + (size_t)(k0 + r)*Ddim + ((g ^ (r & 7)) << 3);
      GLDS16(gp, &Ks[buf][idx*8]);
    }
    #pragma unroll
    for (int i=0;i<8;i++){            // V^T tile: 32 KiB
      int idx = i*256 + tid;
      int d = idx >> 3, g = idx & 7;
      const short* gp = Vtb + (size_t)d*Gdim + k0 + ((g ^ (d & 7)) << 3);
      GLDS16(gp, &Vs[buf][idx*8]);
    }
  };

  s8v qf0[8], qf1[8];
  #pragma unroll
  for (int s=0;s<8;s++){
    qf0[s] = ld8(Qb + (size_t)(qbase + l16)*Ddim + s*32 + quad*8);
    qf1[s] = ld8(Qb + (size_t)(qbase + 16 + l16)*Ddim + s*32 + quad*8);
  }
  float mrow0[4], lrow0[4], mrow1[4], lrow1[4];
  #pragma unroll
  for (int r=0;r<4;r++){ mrow0[r]=mrow1[r]=-1e9f; lrow0[r]=lrow1[r]=0.f; }
  f4v O0[16], O1[16];
  #pragma unroll
  for (int t=0;t<16;t++){ O0[t]=f4v{0.f,0.f,0.f,0.f}; O1[t]=f4v{0.f,0.f,0.f,0.f}; }
  short* Pw = Ps[wave];

  stage(0, 0);
  __syncthreads();
  int cur = 0;
  for (int kt=0; kt<16; kt++){
    const int k0 = kt*64;
    if (kt < 15) stage(cur^1, k0 + 64);   // prefetch next tile, other buffer
    int mk[4];
    #pragma unroll
    for (int tj=0;tj<4;tj++) mk[tj] = mask[b*Gdim + k0 + tj*16 + l16];
    // ---- QK^T from LDS (swizzled reads); each kb feeds both row-tiles
    f4v sc0[4], sc1[4];
    #pragma unroll
    for (int tj=0;tj<4;tj++){ sc0[tj]=f4v{0.f,0.f,0.f,0.f}; sc1[tj]=f4v{0.f,0.f,0.f,0.f}; }
    const short* Kc = &Ks[cur][0];
    #pragma unroll
    for (int st=0; st<8; st++){
      #pragma unroll
      for (int tj=0;tj<4;tj++){
        int row = tj*16 + l16;
        s8v kb = ld8(Kc + row*256 + (((st*4 + quad) ^ (row & 7)) << 3));
        sc0[tj] = MFMA_BF16(qf0[st], kb, sc0[tj]);
        sc1[tj] = MFMA_BF16(qf1[st], kb, sc1[tj]);
      }
    }
    // ---- online softmax (semantics: masked -> -30, stays in denominator,
    //      zeroed in numerator) for each 16-row tile
    auto smax = [&](f4v* sc, float* mr, float* lr, f4v* O){
      float al[4]; bool need = false;
      #pragma unroll
      for (int r=0;r<4;r++){
        float mx = -1e9f;
        #pragma unroll
        for (int tj=0;tj<4;tj++){
          float v = sc[tj][r] * 0.0625f;
          if (mk[tj]) v = -30.f;
          sc[tj][r] = v;
          mx = fmaxf(mx, v);
        }
        #pragma unroll
        for (int mm=1; mm<16; mm<<=1) mx = fmaxf(mx, __shfl_xor(mx, mm));
        float mn = fmaxf(mr[r], mx);
        al[r] = __expf(mr[r] - mn);
        need |= (al[r] < 1.f);
        mr[r] = mn;
        float ps = 0.f;
        #pragma unroll
        for (int tj=0;tj<4;tj++){
          float e = __expf(sc[tj][r] - mn);
          ps += e;
          sc[tj][r] = mk[tj] ? 0.f : e;
        }
        #pragma unroll
        for (int mm=1; mm<16; mm<<=1) ps += __shfl_xor(ps, mm);
        lr[r] = lr[r]*al[r] + ps;
      }
      if (__any(need)){
        #pragma unroll
        for (int t=0;t<16;t++)
          #pragma unroll
          for (int r=0;r<4;r++) O[t][r] *= al[r];
      }
    };
    smax(sc0, mrow0, lrow0, O0);
    smax(sc1, mrow1, lrow1, O1);
    // ---- P transpose through wave-private LDS (intra-wave ordering only)
    #pragma unroll
    for (int tj=0;tj<4;tj++)
      #pragma unroll
      for (int r=0;r<4;r++){
        Pw[(quad*4 + r)*72 + tj*16 + l16]      = f2bf(sc0[tj][r]);
        Pw[(16 + quad*4 + r)*72 + tj*16 + l16] = f2bf(sc1[tj][r]);
      }
    asm volatile("s_waitcnt lgkmcnt(0)" ::: "memory");
    __builtin_amdgcn_sched_barrier(0);
    // ---- PV from LDS (swizzled reads); each vb feeds both row-tiles
    const short* Vc = &Vs[cur][0];
    #pragma unroll
    for (int st=0; st<2; st++){
      s8v pa0 = ld8(&Pw[l16*72 + st*32 + quad*8]);
      s8v pa1 = ld8(&Pw[(16 + l16)*72 + st*32 + quad*8]);
      #pragma unroll
      for (int tt=0; tt<16; tt++){
        int d = tt*16 + l16;
        s8v vb = ld8(Vc + d*64 + (((st*4 + quad) ^ (d & 7)) << 3));
        O0[tt] = MFMA_BF16(pa0, vb, O0[tt]);
        O1[tt] = MFMA_BF16(pa1, vb, O1[tt]);
      }
    }
    __syncthreads();   // drains vmcnt (stages done long ago) + lgkm; flips safe
    cur ^= 1;
  }
  #pragma unroll
  for (int t=0;t<16;t++){
    #pragma unroll
    for (int r=0;r<4;r++){
      int col = t*16 + l16;
      int row0 = qbase + quad*4 + r;
      H[((size_t)b*Gdim + row0)*Ddim + col] = f2bf(O0[t][r] / fmaxf(lrow0[r], 1e-30f));
      int row1 = qbase + 16 + quad*4 + r;
      H[((size_t)b*Gdim + row1)*Ddim + col] = f2bf(O1[t][r] / fmaxf(lrow1[r], 1e-30f));
    }
  }
}

// ------------------------------------------------------------ mean + output
__global__ __launch_bounds__(256) void mean_partial(const float* __restrict__ h32,
                                                    float* __restrict__ part){
  int b = blockIdx.x, c = blockIdx.y, d = threadIdx.x;
  float s = 0.f;
  for (int g = c*64; g < c*64 + 64; g++)
    s += h32[((size_t)b*Gdim + g)*Ddim + d];
  part[(b*16 + c)*Ddim + d] = s;
}
__global__ __launch_bounds__(256) void mean_final_dyn(const float* __restrict__ part,
                                                      void* __restrict__ out,
                                                      const int* __restrict__ flag){
  int i = blockIdx.x*256 + threadIdx.x;
  int b = i >> 8, d = i & 255;
  float s = 0.f;
  #pragma unroll
  for (int c=0;c<16;c++) s += part[(b*16 + c)*Ddim + d];
  s *= (1.f/1024.f);
  if (flag[0]) ((float*)out)[16777216 + i] = s;
  else         ((short*)out)[16777216 + i] = f2bf(s);
}
__global__ __launch_bounds__(256) void store_h(const float* __restrict__ h32,
                                               void* __restrict__ out,
                                               const int* __restrict__ flag){
  size_t i = (size_t)blockIdx.x*256 + threadIdx.x;
  if (flag[0]) ((float*)out)[i] = h32[i];
  else         ((short*)out)[i] = f2bf(h32[i]);
}

// ------------------------------------------------------------ launch
extern "C" void kernel_launch(void* const* d_in, const int* in_sizes, int n_in,
                              void* d_out, int out_size, void* d_ws, size_t ws_size,
                              hipStream_t stream)
{
  const void* xs  = d_in[0];
  const int*  mask= (const int*)d_in[1];
  const void* Wq  = d_in[2];
  const void* Wk  = d_in[3];
  const void* Wv  = d_in[4];
  const void* Wo  = d_in[5];
  const void* bo  = d_in[6];
  const void* Wf1 = d_in[7];
  const void* bf1 = d_in[8];
  const void* Wf2 = d_in[9];
  const void* bf2 = d_in[10];

  // weights: Wqkv(768K) + Wo(256K) + Wf1(1M) + Wf2(1M) + biasf(12K)
  const size_t W_ALL = 786432 + 262144 + 1048576 + 1048576 + 12288;  // 3,158,016
  const size_t BASE  = 256 + 67108864;                               // flag + h32
  int CB;
  if      (ws_size >= BASE + 134217728ull + W_ALL) CB = 64;   // 204.5 MB
  else if (ws_size >= BASE +  67108864ull + W_ALL) CB = 32;   // 137.4 MB (proven reachable)
  else if (ws_size >= BASE +  33554432ull + W_ALL) CB = 16;
  else CB = 0;

  char* p = (char*)d_ws;
  int* flag = (int*)p; p += 256;
  detect_dtype<<<1, 256, 0, stream>>>((const unsigned*)xs, flag);
  if (CB == 0){
    diag_ws<<<1, 64, 0, stream>>>(d_out, 2000.f + (float)(ws_size >> 20), flag);
    return;
  }
  const int M = CB * 1024, nch = 64 / CB;
  float* h32 = (float*)p; p += 67108864;
  char* arena = p;        p += (size_t)CB * 2097152;
  short* WqkvT = (short*)p; p += 786432;
  short* WoT   = (short*)p; p += 262144;
  short* Wf1T  = (short*)p; p += 1048576;
  short* Wf2T  = (short*)p; p += 1048576;
  float* biasf = (float*)p; p += 12288;
  float* part  = (float*)arena;          // arena dead by mean time

  short* Qc  = (short*)arena;
  short* Kc  = Qc + (size_t)M*256;
  short* Vtc = Qc + (size_t)2*M*256;
  short* Hc  = Qc + (size_t)3*M*256;
  short* Tc  = Qc;                       // FFN intermediate spans whole arena

  cast_in<<<8192, 256, 0, stream>>>(xs, h32, flag);
  dim3 tb(32,8);
  transpose_w<<<dim3(8,8,2),  tb, 0, stream>>>(Wq,  WqkvT, 256, 256,  flag, 196608, 0);
  transpose_w<<<dim3(8,8,2),  tb, 0, stream>>>(Wk,  WqkvT, 256, 256,  flag, 196608, 65536);
  transpose_w<<<dim3(8,8,2),  tb, 0, stream>>>(Wv,  WqkvT, 256, 256,  flag, 196608, 131072);
  transpose_w<<<dim3(8,8,2),  tb, 0, stream>>>(Wo,  WoT,   256, 256,  flag, 65536, 0);
  transpose_w<<<dim3(32,8,2), tb, 0, stream>>>(Wf1, Wf1T,  256, 1024, flag, 262144, 0);
  transpose_w<<<dim3(8,32,2), tb, 0, stream>>>(Wf2, Wf2T,  1024, 256, flag, 262144, 0);
  bias_prep<<<12, 256, 0, stream>>>(bo, bf1, bf2, biasf, flag);

  for (int c=0; c<nch; c++){
    float* hc = h32 + (size_t)c*M*256;
    const int* mc = mask + (size_t)c*M;
    for (int l=0; l<2; l++){
      // fused QKV: A = h fp32 (hi), B = stacked [768][256]
      gemm_t<1,5><<<dim3(M/128,6), 256, 0, stream>>>(hc, WqkvT + l*196608, nullptr,
                                                     nullptr, Qc, 768, 256, 256, 256, M);
      flash_attn<<<dim3(8*CB), 256, 0, stream>>>(Qc, Kc, Vtc, mc, Hc);
      // O-proj: h32 += Hc*Wo + bo
      gemm_t<0,4><<<dim3(M/128,2), 256, 0, stream>>>(Hc, WoT + l*65536, biasf + l*256,
                                                     hc, nullptr, 256, 256, 256, 256, M);
      // FFN1: T = relu(h*Wf1 + b), A split
      gemm_t<2,1><<<dim3(M/128,8), 256, 0, stream>>>(hc, Wf1T + l*262144, biasf + 512 + l*1024,
                                                     nullptr, Tc, 1024, 256, 256, 256, M);
      // FFN2: h32 += T*Wf2 + b
      gemm_t<0,4><<<dim3(M/128,2), 256, 0, stream>>>(Tc, Wf2T + l*262144, biasf + 2560 + l*256,
                                                     hc, nullptr, 256, 1024, 1024, 1024, M);
    }
  }
  mean_partial<<<dim3(64,16), 256, 0, stream>>>(h32, part);
  store_h<<<65536, 256, 0, stream>>>(h32, d_out, flag);
  mean_final_dyn<<<64, 256, 0, stream>>>(part, d_out, flag);
}

// Round 3
// 1196.467 us; speedup vs baseline: 1.5495x; 1.1276x over previous
//
#include <hip/hip_runtime.h>
#include <hip/hip_bf16.h>

#define Bdim 64
#define Gdim 1024
#define Ddim 256
#define Fdim 1024

typedef short s8v __attribute__((ext_vector_type(8)));
typedef float f4v __attribute__((ext_vector_type(4)));

__device__ __forceinline__ float bf2f(short s){
  return __uint_as_float(((unsigned)(unsigned short)s) << 16);
}
__device__ __forceinline__ short f2bf(float f){
  unsigned u = __float_as_uint(f);
  u = u + 0x7fffu + ((u >> 16) & 1u);   // RNE
  return (short)(u >> 16);
}
__device__ __forceinline__ s8v ld8(const short* p){ return *(const s8v*)p; }

#define MFMA_BF16(a,b,c) __builtin_amdgcn_mfma_f32_16x16x32_bf16((a),(b),(c),0,0,0)

// async 16B global->LDS (linear dest; swizzle done on the SOURCE address)
#define GLDS16(gp, lp) __builtin_amdgcn_global_load_lds( \
    (const __attribute__((address_space(1))) void*)(gp), \
    (__attribute__((address_space(3))) void*)(lp), 16, 0, 0)

// ------------------------------------------------------------ dtype detection
__global__ __launch_bounds__(256) void detect_dtype(const unsigned* __restrict__ x,
                                                    int* __restrict__ flag){
  __shared__ int cnt[256];
  int c = 0;
  #pragma unroll
  for (int j=0;j<4;j++){
    unsigned u = x[threadIdx.x*4 + j];
    int e = (u >> 7) & 0xFF;
    c += (e >= 100 && e <= 140) ? 1 : 0;
  }
  cnt[threadIdx.x] = c;
  __syncthreads();
  if (threadIdx.x == 0){
    int s = 0;
    for (int i=0;i<256;i++) s += cnt[i];
    flag[0] = (s >= 512) ? 0 : 1;   // 0 = bf16 inputs, 1 = fp32 inputs
  }
}

// ------------------------------------------------------------ diagnostic
__global__ void diag_ws(void* o, float v, const int* __restrict__ flag){
  if (threadIdx.x == 0){
    if (flag[0]){ ((float*)o)[0] = v; ((float*)o)[16777216] = v; }
    else        { ((short*)o)[0] = f2bf(v); ((short*)o)[16777216] = f2bf(v); }
  }
}

// ------------------------------------------------------------ input -> fp32 h
__global__ __launch_bounds__(256) void cast_in(const void* __restrict__ x,
                                               float* __restrict__ h32,
                                               const int* __restrict__ flag){
  size_t i = ((size_t)blockIdx.x * 256 + threadIdx.x) * 8;
  if (flag[0]){
    const float* xf = (const float*)x;
    #pragma unroll
    for (int j=0;j<8;j++) h32[i+j] = xf[i+j];
  } else {
    s8v v = ld8((const short*)x + i);
    #pragma unroll
    for (int j=0;j<8;j++) h32[i+j] = bf2f(v[j]);
  }
}

// ------------------------------------------------------------ weight transpose -> bf16, stackable dst
__global__ __launch_bounds__(256) void transpose_w(const void* __restrict__ src,
                                                   short* __restrict__ dh, int R, int C,
                                                   const int* __restrict__ flag,
                                                   int dzs, int dbase){
  __shared__ short th[32][33];
  int fl = flag[0];
  size_t soff = (size_t)blockIdx.z * R * C;
  size_t doff = (size_t)dbase + (size_t)blockIdx.z * dzs;
  int c0 = blockIdx.x*32, r0 = blockIdx.y*32;
  int tx = threadIdx.x, ty = threadIdx.y;
  #pragma unroll
  for (int i=ty;i<32;i+=8){
    size_t idx = soff + (size_t)(r0+i)*C + (c0+tx);
    float w = fl ? ((const float*)src)[idx] : bf2f(((const short*)src)[idx]);
    th[i][tx] = f2bf(w);
  }
  __syncthreads();
  #pragma unroll
  for (int i=ty;i<32;i+=8)
    dh[doff + (size_t)(c0+i)*R + (r0+tx)] = th[tx][i];
}

// ------------------------------------------------------------ biases -> fp32
// [0..511]=bo(2x256)  [512..2559]=bf1(2x1024)  [2560..3071]=bf2(2x256)
__global__ __launch_bounds__(256) void bias_prep(const void* __restrict__ bo,
                                                 const void* __restrict__ bf1,
                                                 const void* __restrict__ bf2,
                                                 float* __restrict__ biasf,
                                                 const int* __restrict__ flag){
  int fl = flag[0];
  int i = blockIdx.x*256 + threadIdx.x;
  const void* src; int idx;
  if (i < 512){ src = bo; idx = i; }
  else if (i < 2560){ src = bf1; idx = i - 512; }
  else { src = bf2; idx = i - 2560; }
  biasf[i] = fl ? ((const float*)src)[idx] : bf2f(((const short*)src)[idx]);
}

// ------------------------------------------------------------ GEMM template
// AM: 0 = A bf16; 1 = A fp32 -> hi only; 2 = A fp32 -> hi+lo split (2 MFMA)
// EPI: 0 = bf16 store; 1 = relu(acc+bias) bf16 store;
//      4 = h32[idx] += acc + bias; 5 = fused QKV routing (Q,K row-major; V transposed)
template<int AM, int EPI>
__global__ __launch_bounds__(256) void gemm_t(
    const void* __restrict__ Ap, const short* __restrict__ Bh,
    const float* __restrict__ bias, float* __restrict__ hout,
    short* __restrict__ outb, int N, int K, int lda, int ldb, int Mrows)
{
  constexpr int AT = (AM==2) ? 2 : 1;
  __shared__ short As[AT*128*40];
  __shared__ short Bs[128*40];
  short* Asl = As + 128*40;
  const int tid = threadIdx.x;
  const int lane = tid & 63, wave = tid >> 6;
  const int quad = lane >> 4, l16 = lane & 15;
  const int m0 = blockIdx.x * 128, n0 = blockIdx.y * 128;
  const int wr = wave >> 1, wc = wave & 1;
  f4v acc[4][4];
  #pragma unroll
  for (int i=0;i<4;i++)
    #pragma unroll
    for (int j=0;j<4;j++) acc[i][j] = f4v{0.f,0.f,0.f,0.f};

  for (int k0 = 0; k0 < K; k0 += 32){
    __syncthreads();
    #pragma unroll
    for (int i=0;i<2;i++){
      int v = tid + i*256;
      int r = v >> 2, c8 = (v & 3) * 8;
      if (AM == 0){
        *(s8v*)(&As[r*40 + c8]) = ld8((const short*)Ap + (size_t)(m0 + r)*lda + k0 + c8);
      } else {
        const float* af = (const float*)Ap + (size_t)(m0 + r)*lda + k0 + c8;
        float4 f0 = *(const float4*)af;
        float4 f1 = *(const float4*)(af + 4);
        float fv[8] = {f0.x,f0.y,f0.z,f0.w,f1.x,f1.y,f1.z,f1.w};
        s8v hi, lo;
        #pragma unroll
        for (int j=0;j<8;j++) hi[j] = f2bf(fv[j]);
        *(s8v*)(&As[r*40 + c8]) = hi;
        if (AM == 2){
          #pragma unroll
          for (int j=0;j<8;j++) lo[j] = f2bf(fv[j] - bf2f(hi[j]));
          *(s8v*)(&Asl[r*40 + c8]) = lo;
        }
      }
      *(s8v*)(&Bs[r*40 + c8]) = ld8(Bh + (size_t)(n0 + r)*ldb + k0 + c8);
    }
    __syncthreads();
    s8v ah[4], al[4], bh[4];
    #pragma unroll
    for (int t=0;t<4;t++){
      ah[t] = ld8(&As[(wr*64 + t*16 + l16)*40 + quad*8]);
      bh[t] = ld8(&Bs[(wc*64 + t*16 + l16)*40 + quad*8]);
      if (AM == 2) al[t] = ld8(&Asl[(wr*64 + t*16 + l16)*40 + quad*8]);
    }
    #pragma unroll
    for (int ti=0;ti<4;ti++)
      #pragma unroll
      for (int tj=0;tj<4;tj++){
        acc[ti][tj] = MFMA_BF16(ah[ti], bh[tj], acc[ti][tj]);
        if (AM == 2) acc[ti][tj] = MFMA_BF16(al[ti], bh[tj], acc[ti][tj]);
      }
  }
  #pragma unroll
  for (int tj=0;tj<4;tj++){
    int col = n0 + wc*64 + tj*16 + l16;
    float bs = (EPI==1 || EPI==4) ? (bias ? bias[col] : 0.f) : 0.f;
    #pragma unroll
    for (int ti=0;ti<4;ti++){
      #pragma unroll
      for (int r=0;r<4;r++){
        int row = m0 + wr*64 + ti*16 + quad*4 + r;
        float v = acc[ti][tj][r];
        if (EPI == 0){
          outb[(size_t)row * N + col] = f2bf(v);
        } else if (EPI == 1){
          v += bs; v = v > 0.f ? v : 0.f;
          outb[(size_t)row * N + col] = f2bf(v);
        } else if (EPI == 4){
          size_t idx = (size_t)row * N + col;
          hout[idx] += v + bs;
        } else {  // EPI == 5: fused QKV
          int sec = col >> 8, c = col & 255;
          if (sec == 0)      outb[(size_t)row*256 + c] = f2bf(v);
          else if (sec == 1) (outb + (size_t)Mrows*256)[(size_t)row*256 + c] = f2bf(v);
          else {
            int bb = row >> 10, g = row & 1023;
            (outb + (size_t)2*Mrows*256)[(size_t)bb*262144 + (size_t)c*1024 + g] = f2bf(v);
          }
        }
      }
    }
  }
}

// ------------------------------------------------------------ flash attention v4
// 8 waves x 16 q-rows = 128 rows/block; 8 blocks/batch; grid 8*CB; 512 thr ->
// 8 waves/CU = 2 waves/SIMD (latency hiding: one wave's softmax VALU chain
// overlaps the SIMD-mate's MFMAs). K,V double-buffered in LDS via async
// global_load_lds (linear dest, XOR-pre-swizzled SOURCE, same XOR on ds_read).
// One __syncthreads per kt. Sum-reduce DEFERRED: per-lane partial lsum with
// the same rescale recurrence; single cross-lane reduce in the epilogue.
// setprio(1) wraps MFMA clusters (T5; pays at 2 waves/SIMD).
__global__ __launch_bounds__(512, 2) void flash_attn(
    const short* __restrict__ Q, const short* __restrict__ Kmat,
    const short* __restrict__ Vt, const int* __restrict__ mask,
    short* __restrict__ H)
{
  __shared__ short Ks[2][64*256];   // 64 KiB: K tile [64 keys][256 d], src-swizzled
  __shared__ short Vs[2][256*64];   // 64 KiB: V^T tile [256 d][64 keys], src-swizzled
  __shared__ short Ps[8][16*72];    // 18 KiB: per-wave P [16 qrows][64 keys]
  const int tid = threadIdx.x;
  const int lane = tid & 63, wave = tid >> 6;   // wave 0..7
  const int quad = lane >> 4, l16 = lane & 15;
  // batch -> XCD pinning: all 8 q-tile blocks of batch b share XCD b&7.
  const int bid = blockIdx.x;
  const int b  = (bid & 7) + ((bid >> 6) << 3);
  const int qt = (bid >> 3) & 7;
  const short* Qb  = Q    + (size_t)b*Gdim*Ddim;
  const short* Kb  = Kmat + (size_t)b*Gdim*Ddim;
  const short* Vtb = Vt   + (size_t)b*Ddim*Gdim;
  const int qbase = qt*128 + wave*16;

  auto stage = [&](int buf, int k0){
    #pragma unroll
    for (int i=0;i<4;i++){            // K tile: 32 KiB, 16B/thread x 4
      int idx = i*512 + tid;
      int r = idx >> 5, g = idx & 31;
      GLDS16(Kb + (size_t)(k0 + r)*Ddim + ((g ^ (r & 7)) << 3), &Ks[buf][idx*8]);
    }
    #pragma unroll
    for (int i=0;i<4;i++){            // V^T tile: 32 KiB
      int idx = i*512 + tid;
      int d = idx >> 3, g = idx & 7;
      GLDS16(Vtb + (size_t)d*Gdim + k0 + ((g ^ (d & 7)) << 3), &Vs[buf][idx*8]);
    }
  };

  s8v qf[8];
  #pragma unroll
  for (int s=0;s<8;s++)
    qf[s] = ld8(Qb + (size_t)(qbase + l16)*Ddim + s*32 + quad*8);
  float mrow[4], lsum[4];
  #pragma unroll
  for (int r=0;r<4;r++){ mrow[r] = -1e9f; lsum[r] = 0.f; }
  f4v O[16];
  #pragma unroll
  for (int t=0;t<16;t++) O[t] = f4v{0.f,0.f,0.f,0.f};
  short* Pw = Ps[wave];

  stage(0, 0);
  __syncthreads();
  int cur = 0;
  for (int kt=0; kt<16; kt++){
    const int k0 = kt*64;
    if (kt < 15) stage(cur^1, k0 + 64);   // prefetch next tile, other buffer
    int mk[4];
    #pragma unroll
    for (int tj=0;tj<4;tj++) mk[tj] = mask[b*Gdim + k0 + tj*16 + l16];
    // ---- QK^T from LDS (swizzled reads)
    f4v sc[4];
    #pragma unroll
    for (int tj=0;tj<4;tj++) sc[tj] = f4v{0.f,0.f,0.f,0.f};
    const short* Kc = &Ks[cur][0];
    __builtin_amdgcn_s_setprio(1);
    #pragma unroll
    for (int st=0; st<8; st++){
      #pragma unroll
      for (int tj=0;tj<4;tj++){
        int row = tj*16 + l16;
        s8v kb = ld8(Kc + row*256 + (((st*4 + quad) ^ (row & 7)) << 3));
        sc[tj] = MFMA_BF16(qf[st], kb, sc[tj]);
      }
    }
    __builtin_amdgcn_s_setprio(0);
    // ---- online softmax; masked -> -30, stays in denominator, zeroed in
    //      numerator. Sum-reduce deferred: lsum is a PER-LANE partial with
    //      the same rescale recurrence (cross-lane add once, in epilogue).
    float al[4]; bool need = false;
    #pragma unroll
    for (int r=0;r<4;r++){
      float mx = -1e9f;
      #pragma unroll
      for (int tj=0;tj<4;tj++){
        float v = sc[tj][r] * 0.0625f;
        if (mk[tj]) v = -30.f;
        sc[tj][r] = v;
        mx = fmaxf(mx, v);
      }
      #pragma unroll
      for (int mm=1; mm<16; mm<<=1) mx = fmaxf(mx, __shfl_xor(mx, mm));
      float mn = fmaxf(mrow[r], mx);
      al[r] = __expf(mrow[r] - mn);
      need |= (al[r] < 1.f);
      mrow[r] = mn;
      float ps = 0.f;
      #pragma unroll
      for (int tj=0;tj<4;tj++){
        float e = __expf(sc[tj][r] - mn);
        ps += e;                         // masked entries stay in denominator
        sc[tj][r] = mk[tj] ? 0.f : e;    // zeroed in numerator
      }
      lsum[r] = lsum[r]*al[r] + ps;      // per-lane partial; no reduce here
    }
    if (__any(need)){
      #pragma unroll
      for (int t=0;t<16;t++)
        #pragma unroll
        for (int r=0;r<4;r++) O[t][r] *= al[r];
    }
    // ---- P transpose through wave-private LDS (intra-wave ordering only)
    #pragma unroll
    for (int tj=0;tj<4;tj++)
      #pragma unroll
      for (int r=0;r<4;r++)
        Pw[(quad*4 + r)*72 + tj*16 + l16] = f2bf(sc[tj][r]);
    asm volatile("s_waitcnt lgkmcnt(0)" ::: "memory");
    __builtin_amdgcn_sched_barrier(0);
    // ---- PV from LDS (swizzled reads)
    const short* Vc = &Vs[cur][0];
    __builtin_amdgcn_s_setprio(1);
    #pragma unroll
    for (int st=0; st<2; st++){
      s8v pa = ld8(&Pw[l16*72 + st*32 + quad*8]);
      #pragma unroll
      for (int tt=0; tt<16; tt++){
        int d = tt*16 + l16;
        s8v vb = ld8(Vc + d*64 + (((st*4 + quad) ^ (d & 7)) << 3));
        O[tt] = MFMA_BF16(pa, vb, O[tt]);
      }
    }
    __builtin_amdgcn_s_setprio(0);
    __syncthreads();   // drains vmcnt (prefetch done) + lgkm; flip safe
    cur ^= 1;
  }
  // ---- deferred cross-lane sum reduce (once, not per kt)
  float dn[4];
  #pragma unroll
  for (int r=0;r<4;r++){
    float s = lsum[r];
    #pragma unroll
    for (int mm=1; mm<16; mm<<=1) s += __shfl_xor(s, mm);
    dn[r] = fmaxf(s, 1e-30f);
  }
  #pragma unroll
  for (int t=0;t<16;t++){
    #pragma unroll
    for (int r=0;r<4;r++){
      int row = qbase + quad*4 + r;
      int col = t*16 + l16;
      H[((size_t)b*Gdim + row)*Ddim + col] = f2bf(O[t][r] / dn[r]);
    }
  }
}

// ------------------------------------------------------------ mean + output
__global__ __launch_bounds__(256) void mean_partial(const float* __restrict__ h32,
                                                    float* __restrict__ part){
  int b = blockIdx.x, c = blockIdx.y, d = threadIdx.x;
  float s = 0.f;
  for (int g = c*64; g < c*64 + 64; g++)
    s += h32[((size_t)b*Gdim + g)*Ddim + d];
  part[(b*16 + c)*Ddim + d] = s;
}
__global__ __launch_bounds__(256) void mean_final_dyn(const float* __restrict__ part,
                                                      void* __restrict__ out,
                                                      const int* __restrict__ flag){
  int i = blockIdx.x*256 + threadIdx.x;
  int b = i >> 8, d = i & 255;
  float s = 0.f;
  #pragma unroll
  for (int c=0;c<16;c++) s += part[(b*16 + c)*Ddim + d];
  s *= (1.f/1024.f);
  if (flag[0]) ((float*)out)[16777216 + i] = s;
  else         ((short*)out)[16777216 + i] = f2bf(s);
}
__global__ __launch_bounds__(256) void store_h(const float* __restrict__ h32,
                                               void* __restrict__ out,
                                               const int* __restrict__ flag){
  size_t i = (size_t)blockIdx.x*256 + threadIdx.x;
  if (flag[0]) ((float*)out)[i] = h32[i];
  else         ((short*)out)[i] = f2bf(h32[i]);
}

// ------------------------------------------------------------ launch
extern "C" void kernel_launch(void* const* d_in, const int* in_sizes, int n_in,
                              void* d_out, int out_size, void* d_ws, size_t ws_size,
                              hipStream_t stream)
{
  const void* xs  = d_in[0];
  const int*  mask= (const int*)d_in[1];
  const void* Wq  = d_in[2];
  const void* Wk  = d_in[3];
  const void* Wv  = d_in[4];
  const void* Wo  = d_in[5];
  const void* bo  = d_in[6];
  const void* Wf1 = d_in[7];
  const void* bf1 = d_in[8];
  const void* Wf2 = d_in[9];
  const void* bf2 = d_in[10];

  // weights: Wqkv(768K) + Wo(256K) + Wf1(1M) + Wf2(1M) + biasf(12K)
  const size_t W_ALL = 786432 + 262144 + 1048576 + 1048576 + 12288;  // 3,158,016
  const size_t BASE  = 256 + 67108864;                               // flag + h32
  int CB;
  if      (ws_size >= BASE + 134217728ull + W_ALL) CB = 64;   // 204.5 MB
  else if (ws_size >= BASE +  67108864ull + W_ALL) CB = 32;   // 137.4 MB (proven reachable)
  else if (ws_size >= BASE +  33554432ull + W_ALL) CB = 16;
  else CB = 0;

  char* p = (char*)d_ws;
  int* flag = (int*)p; p += 256;
  detect_dtype<<<1, 256, 0, stream>>>((const unsigned*)xs, flag);
  if (CB == 0){
    diag_ws<<<1, 64, 0, stream>>>(d_out, 2000.f + (float)(ws_size >> 20), flag);
    return;
  }
  const int M = CB * 1024, nch = 64 / CB;
  float* h32 = (float*)p; p += 67108864;
  char* arena = p;        p += (size_t)CB * 2097152;
  short* WqkvT = (short*)p; p += 786432;
  short* WoT   = (short*)p; p += 262144;
  short* Wf1T  = (short*)p; p += 1048576;
  short* Wf2T  = (short*)p; p += 1048576;
  float* biasf = (float*)p; p += 12288;
  float* part  = (float*)arena;          // arena dead by mean time

  short* Qc  = (short*)arena;
  short* Kc  = Qc + (size_t)M*256;
  short* Vtc = Qc + (size_t)2*M*256;
  short* Hc  = Qc + (size_t)3*M*256;
  short* Tc  = Qc;                       // FFN intermediate spans whole arena

  cast_in<<<8192, 256, 0, stream>>>(xs, h32, flag);
  dim3 tb(32,8);
  transpose_w<<<dim3(8,8,2),  tb, 0, stream>>>(Wq,  WqkvT, 256, 256,  flag, 196608, 0);
  transpose_w<<<dim3(8,8,2),  tb, 0, stream>>>(Wk,  WqkvT, 256, 256,  flag, 196608, 65536);
  transpose_w<<<dim3(8,8,2),  tb, 0, stream>>>(Wv,  WqkvT, 256, 256,  flag, 196608, 131072);
  transpose_w<<<dim3(8,8,2),  tb, 0, stream>>>(Wo,  WoT,   256, 256,  flag, 65536, 0);
  transpose_w<<<dim3(32,8,2), tb, 0, stream>>>(Wf1, Wf1T,  256, 1024, flag, 262144, 0);
  transpose_w<<<dim3(8,32,2), tb, 0, stream>>>(Wf2, Wf2T,  1024, 256, flag, 262144, 0);
  bias_prep<<<12, 256, 0, stream>>>(bo, bf1, bf2, biasf, flag);

  for (int c=0; c<nch; c++){
    float* hc = h32 + (size_t)c*M*256;
    const int* mc = mask + (size_t)c*M;
    for (int l=0; l<2; l++){
      // fused QKV: A = h fp32 (hi), B = stacked [768][256]
      gemm_t<1,5><<<dim3(M/128,6), 256, 0, stream>>>(hc, WqkvT + l*196608, nullptr,
                                                     nullptr, Qc, 768, 256, 256, 256, M);
      flash_attn<<<dim3(8*CB), 512, 0, stream>>>(Qc, Kc, Vtc, mc, Hc);
      // O-proj: h32 += Hc*Wo + bo
      gemm_t<0,4><<<dim3(M/128,2), 256, 0, stream>>>(Hc, WoT + l*65536, biasf + l*256,
                                                     hc, nullptr, 256, 256, 256, 256, M);
      // FFN1: T = relu(h*Wf1 + b), A split
      gemm_t<2,1><<<dim3(M/128,8), 256, 0, stream>>>(hc, Wf1T + l*262144, biasf + 512 + l*1024,
                                                     nullptr, Tc, 1024, 256, 256, 256, M);
      // FFN2: h32 += T*Wf2 + b
      gemm_t<0,4><<<dim3(M/128,2), 256, 0, stream>>>(Tc, Wf2T + l*262144, biasf + 2560 + l*256,
                                                     hc, nullptr, 256, 1024, 1024, 1024, M);
    }
  }
  mean_partial<<<dim3(64,16), 256, 0, stream>>>(h32, part);
  store_h<<<65536, 256, 0, stream>>>(h32, d_out, flag);
  mean_final_dyn<<<64, 256, 0, stream>>>(part, d_out, flag);
}

// Round 4
// 1175.627 us; speedup vs baseline: 1.5769x; 1.0177x over previous
//
#include <hip/hip_runtime.h>
#include <hip/hip_bf16.h>

#define Bdim 64
#define Gdim 1024
#define Ddim 256
#define Fdim 1024

typedef short s8v __attribute__((ext_vector_type(8)));
typedef short s4v __attribute__((ext_vector_type(4)));
typedef float f4v __attribute__((ext_vector_type(4)));

__device__ __forceinline__ float bf2f(short s){
  return __uint_as_float(((unsigned)(unsigned short)s) << 16);
}
__device__ __forceinline__ short f2bf(float f){
  unsigned u = __float_as_uint(f);
  u = u + 0x7fffu + ((u >> 16) & 1u);   // RNE
  return (short)(u >> 16);
}
__device__ __forceinline__ s8v ld8(const short* p){ return *(const s8v*)p; }

#define MFMA_BF16(a,b,c) __builtin_amdgcn_mfma_f32_16x16x32_bf16((a),(b),(c),0,0,0)

// async 16B global->LDS (linear dest; swizzle done on the SOURCE address)
#define GLDS16(gp, lp) __builtin_amdgcn_global_load_lds( \
    (const __attribute__((address_space(1))) void*)(gp), \
    (__attribute__((address_space(3))) void*)(lp), 16, 0, 0)

// ------------------------------------------------------------ dtype detection
__global__ __launch_bounds__(256) void detect_dtype(const unsigned* __restrict__ x,
                                                    int* __restrict__ flag){
  __shared__ int cnt[256];
  int c = 0;
  #pragma unroll
  for (int j=0;j<4;j++){
    unsigned u = x[threadIdx.x*4 + j];
    int e = (u >> 7) & 0xFF;
    c += (e >= 100 && e <= 140) ? 1 : 0;
  }
  cnt[threadIdx.x] = c;
  __syncthreads();
  if (threadIdx.x == 0){
    int s = 0;
    for (int i=0;i<256;i++) s += cnt[i];
    flag[0] = (s >= 512) ? 0 : 1;   // 0 = bf16 inputs, 1 = fp32 inputs
  }
}

// ------------------------------------------------------------ diagnostic
__global__ void diag_ws(void* o, float v, const int* __restrict__ flag){
  if (threadIdx.x == 0){
    if (flag[0]){ ((float*)o)[0] = v; ((float*)o)[16777216] = v; }
    else        { ((short*)o)[0] = f2bf(v); ((short*)o)[16777216] = f2bf(v); }
  }
}

// ------------------------------------------------------------ input -> fp32 h
__global__ __launch_bounds__(256) void cast_in(const void* __restrict__ x,
                                               float* __restrict__ h32,
                                               const int* __restrict__ flag){
  size_t i = ((size_t)blockIdx.x * 256 + threadIdx.x) * 8;
  if (flag[0]){
    const float* xf = (const float*)x;
    #pragma unroll
    for (int j=0;j<8;j++) h32[i+j] = xf[i+j];
  } else {
    s8v v = ld8((const short*)x + i);
    #pragma unroll
    for (int j=0;j<8;j++) h32[i+j] = bf2f(v[j]);
  }
}

// ------------------------------------------------------------ weight transpose -> bf16, stackable dst
__global__ __launch_bounds__(256) void transpose_w(const void* __restrict__ src,
                                                   short* __restrict__ dh, int R, int C,
                                                   const int* __restrict__ flag,
                                                   int dzs, int dbase){
  __shared__ short th[32][33];
  int fl = flag[0];
  size_t soff = (size_t)blockIdx.z * R * C;
  size_t doff = (size_t)dbase + (size_t)blockIdx.z * dzs;
  int c0 = blockIdx.x*32, r0 = blockIdx.y*32;
  int tx = threadIdx.x, ty = threadIdx.y;
  #pragma unroll
  for (int i=ty;i<32;i+=8){
    size_t idx = soff + (size_t)(r0+i)*C + (c0+tx);
    float w = fl ? ((const float*)src)[idx] : bf2f(((const short*)src)[idx]);
    th[i][tx] = f2bf(w);
  }
  __syncthreads();
  #pragma unroll
  for (int i=ty;i<32;i+=8)
    dh[doff + (size_t)(c0+i)*R + (r0+tx)] = th[tx][i];
}

// ------------------------------------------------------------ biases -> fp32
// [0..511]=bo(2x256)  [512..2559]=bf1(2x1024)  [2560..3071]=bf2(2x256)
__global__ __launch_bounds__(256) void bias_prep(const void* __restrict__ bo,
                                                 const void* __restrict__ bf1,
                                                 const void* __restrict__ bf2,
                                                 float* __restrict__ biasf,
                                                 const int* __restrict__ flag){
  int fl = flag[0];
  int i = blockIdx.x*256 + threadIdx.x;
  const void* src; int idx;
  if (i < 512){ src = bo; idx = i; }
  else if (i < 2560){ src = bf1; idx = i - 512; }
  else { src = bf2; idx = i - 2560; }
  biasf[i] = fl ? ((const float*)src)[idx] : bf2f(((const short*)src)[idx]);
}

// ------------------------------------------------------------ GEMM template
// AM: 0 = A bf16; 1 = A fp32 -> hi only; 2 = A fp32 -> hi+lo split (2 MFMA)
// EPI: 0 = bf16 store; 1 = relu(acc+bias) bf16 store;
//      4 = h32[idx] += acc + bias; 5 = fused QKV routing (Q,K row-major; V transposed)
template<int AM, int EPI>
__global__ __launch_bounds__(256) void gemm_t(
    const void* __restrict__ Ap, const short* __restrict__ Bh,
    const float* __restrict__ bias, float* __restrict__ hout,
    short* __restrict__ outb, int N, int K, int lda, int ldb, int Mrows)
{
  constexpr int AT = (AM==2) ? 2 : 1;
  __shared__ short As[AT*128*40];
  __shared__ short Bs[128*40];
  short* Asl = As + 128*40;
  const int tid = threadIdx.x;
  const int lane = tid & 63, wave = tid >> 6;
  const int quad = lane >> 4, l16 = lane & 15;
  const int m0 = blockIdx.x * 128, n0 = blockIdx.y * 128;
  const int wr = wave >> 1, wc = wave & 1;
  f4v acc[4][4];
  #pragma unroll
  for (int i=0;i<4;i++)
    #pragma unroll
    for (int j=0;j<4;j++) acc[i][j] = f4v{0.f,0.f,0.f,0.f};

  for (int k0 = 0; k0 < K; k0 += 32){
    __syncthreads();
    #pragma unroll
    for (int i=0;i<2;i++){
      int v = tid + i*256;
      int r = v >> 2, c8 = (v & 3) * 8;
      if (AM == 0){
        *(s8v*)(&As[r*40 + c8]) = ld8((const short*)Ap + (size_t)(m0 + r)*lda + k0 + c8);
      } else {
        const float* af = (const float*)Ap + (size_t)(m0 + r)*lda + k0 + c8;
        float4 f0 = *(const float4*)af;
        float4 f1 = *(const float4*)(af + 4);
        float fv[8] = {f0.x,f0.y,f0.z,f0.w,f1.x,f1.y,f1.z,f1.w};
        s8v hi, lo;
        #pragma unroll
        for (int j=0;j<8;j++) hi[j] = f2bf(fv[j]);
        *(s8v*)(&As[r*40 + c8]) = hi;
        if (AM == 2){
          #pragma unroll
          for (int j=0;j<8;j++) lo[j] = f2bf(fv[j] - bf2f(hi[j]));
          *(s8v*)(&Asl[r*40 + c8]) = lo;
        }
      }
      *(s8v*)(&Bs[r*40 + c8]) = ld8(Bh + (size_t)(n0 + r)*ldb + k0 + c8);
    }
    __syncthreads();
    s8v ah[4], al[4], bh[4];
    #pragma unroll
    for (int t=0;t<4;t++){
      ah[t] = ld8(&As[(wr*64 + t*16 + l16)*40 + quad*8]);
      bh[t] = ld8(&Bs[(wc*64 + t*16 + l16)*40 + quad*8]);
      if (AM == 2) al[t] = ld8(&Asl[(wr*64 + t*16 + l16)*40 + quad*8]);
    }
    #pragma unroll
    for (int ti=0;ti<4;ti++)
      #pragma unroll
      for (int tj=0;tj<4;tj++){
        acc[ti][tj] = MFMA_BF16(ah[ti], bh[tj], acc[ti][tj]);
        if (AM == 2) acc[ti][tj] = MFMA_BF16(al[ti], bh[tj], acc[ti][tj]);
      }
  }
  #pragma unroll
  for (int tj=0;tj<4;tj++){
    int col = n0 + wc*64 + tj*16 + l16;
    float bs = (EPI==1 || EPI==4) ? (bias ? bias[col] : 0.f) : 0.f;
    #pragma unroll
    for (int ti=0;ti<4;ti++){
      #pragma unroll
      for (int r=0;r<4;r++){
        int row = m0 + wr*64 + ti*16 + quad*4 + r;
        float v = acc[ti][tj][r];
        if (EPI == 0){
          outb[(size_t)row * N + col] = f2bf(v);
        } else if (EPI == 1){
          v += bs; v = v > 0.f ? v : 0.f;
          outb[(size_t)row * N + col] = f2bf(v);
        } else if (EPI == 4){
          size_t idx = (size_t)row * N + col;
          hout[idx] += v + bs;
        } else {  // EPI == 5: fused QKV
          int sec = col >> 8, c = col & 255;
          if (sec == 0)      outb[(size_t)row*256 + c] = f2bf(v);
          else if (sec == 1) (outb + (size_t)Mrows*256)[(size_t)row*256 + c] = f2bf(v);
          else {
            int bb = row >> 10, g = row & 1023;
            (outb + (size_t)2*Mrows*256)[(size_t)bb*262144 + (size_t)c*1024 + g] = f2bf(v);
          }
        }
      }
    }
  }
}

// ------------------------------------------------------------ flash attention v5
// 8 waves x 16 q-rows = 128 rows/block; 8 blocks/batch; grid 8*CB; 512 thr.
// SWAPPED QK^T: sc = MFMA(K_frag, Q_frag) -> C[row=key, col=query]; each lane
// owns ONE query (l16) x 16 keys in registers. Softmax row-max becomes an
// in-register tree + 2 cross-quad shuffles (was 4x 4-step shuffle chains).
// Mask via one __ballot bitmap per kt (load hidden under QK^T MFMAs).
// T13 defer-max (THR=8): O-rescale skipped unless max grows by >8.
// P-store: 4x ds_write_b64 (consecutive keys per lane), was 16x ds_write_b16.
// K,V double-buffered LDS via global_load_lds (src-XOR-swizzle); one
// __syncthreads per kt; sum-reduce deferred to epilogue.
__global__ __launch_bounds__(512, 2) void flash_attn(
    const short* __restrict__ Q, const short* __restrict__ Kmat,
    const short* __restrict__ Vt, const int* __restrict__ mask,
    short* __restrict__ H)
{
  __shared__ short Ks[2][64*256];   // 64 KiB: K tile [64 keys][256 d], src-swizzled
  __shared__ short Vs[2][256*64];   // 64 KiB: V^T tile [256 d][64 keys], src-swizzled
  __shared__ short Ps[8][16*72];    // 18 KiB: per-wave P [16 qrows][64 keys]
  const int tid = threadIdx.x;
  const int lane = tid & 63, wave = tid >> 6;   // wave 0..7
  const int quad = lane >> 4, l16 = lane & 15;
  // batch -> XCD pinning: all 8 q-tile blocks of batch b share XCD b&7.
  const int bid = blockIdx.x;
  const int b  = (bid & 7) + ((bid >> 6) << 3);
  const int qt = (bid >> 3) & 7;
  const short* Qb  = Q    + (size_t)b*Gdim*Ddim;
  const short* Kb  = Kmat + (size_t)b*Gdim*Ddim;
  const short* Vtb = Vt   + (size_t)b*Ddim*Gdim;
  const int qbase = qt*128 + wave*16;

  auto stage = [&](int buf, int k0){
    #pragma unroll
    for (int i=0;i<4;i++){            // K tile: 32 KiB, 16B/thread x 4
      int idx = i*512 + tid;
      int r = idx >> 5, g = idx & 31;
      GLDS16(Kb + (size_t)(k0 + r)*Ddim + ((g ^ (r & 7)) << 3), &Ks[buf][idx*8]);
    }
    #pragma unroll
    for (int i=0;i<4;i++){            // V^T tile: 32 KiB
      int idx = i*512 + tid;
      int d = idx >> 3, g = idx & 7;
      GLDS16(Vtb + (size_t)d*Gdim + k0 + ((g ^ (d & 7)) << 3), &Vs[buf][idx*8]);
    }
  };

  s8v qf[8];
  #pragma unroll
  for (int s=0;s<8;s++)
    qf[s] = ld8(Qb + (size_t)(qbase + l16)*Ddim + s*32 + quad*8);
  float mrow = -1e9f, lsum = 0.f;    // scalar per lane (query = l16)
  f4v O[16];
  #pragma unroll
  for (int t=0;t<16;t++) O[t] = f4v{0.f,0.f,0.f,0.f};
  short* Pw = Ps[wave];

  stage(0, 0);
  __syncthreads();
  int cur = 0;
  for (int kt=0; kt<16; kt++){
    const int k0 = kt*64;
    if (kt < 15) stage(cur^1, k0 + 64);   // prefetch next tile, other buffer
    int mv = mask[b*Gdim + k0 + lane];    // issued early; ballot after QK^T
    // ---- swapped QK^T from LDS: C[row=key, col=query=l16]
    f4v sc[4];
    #pragma unroll
    for (int tj=0;tj<4;tj++) sc[tj] = f4v{0.f,0.f,0.f,0.f};
    const short* Kc = &Ks[cur][0];
    __builtin_amdgcn_s_setprio(1);
    #pragma unroll
    for (int st=0; st<8; st++){
      #pragma unroll
      for (int tj=0;tj<4;tj++){
        int row = tj*16 + l16;
        s8v kb = ld8(Kc + row*256 + (((st*4 + quad) ^ (row & 7)) << 3));
        sc[tj] = MFMA_BF16(kb, qf[st], sc[tj]);   // SWAPPED operands
      }
    }
    __builtin_amdgcn_s_setprio(0);
    // ---- lane-local softmax. Lane holds S(q=l16, key=tj*16+quad*4+r).
    unsigned long long mb = __ballot(mv != 0);
    float pm = -1e9f;
    #pragma unroll
    for (int tj=0;tj<4;tj++){
      unsigned mb4 = (unsigned)(mb >> (tj*16 + quad*4)) & 15u;
      #pragma unroll
      for (int r=0;r<4;r++){
        float v = sc[tj][r] * 0.0625f;
        if ((mb4 >> r) & 1u) v = -30.f;
        sc[tj][r] = v;
        pm = fmaxf(pm, v);
      }
    }
    pm = fmaxf(pm, __shfl_xor(pm, 16));   // cross-quad (same query)
    pm = fmaxf(pm, __shfl_xor(pm, 32));
    if (!__all(pm <= mrow + 8.f)){        // T13 defer-max, THR=8
      float mn = fmaxf(mrow, pm);
      float al = __expf(mrow - mn);
      mrow = mn;
      lsum *= al;
      float alr[4];
      #pragma unroll
      for (int r=0;r<4;r++) alr[r] = __shfl(al, quad*4 + r);
      #pragma unroll
      for (int t=0;t<16;t++)
        #pragma unroll
        for (int r=0;r<4;r++) O[t][r] *= alr[r];
    }
    float ps = 0.f;
    #pragma unroll
    for (int tj=0;tj<4;tj++){
      unsigned mb4 = (unsigned)(mb >> (tj*16 + quad*4)) & 15u;
      s4v pk;
      #pragma unroll
      for (int r=0;r<4;r++){
        float e = __expf(sc[tj][r] - mrow);   // bounded by e^8 under defer
        ps += e;                               // masked stay in denominator
        pk[r] = ((mb4 >> r) & 1u) ? (short)0 : f2bf(e);  // zeroed in numerator
      }
      *(s4v*)(&Pw[l16*72 + tj*16 + quad*4]) = pk;   // ds_write_b64
    }
    lsum += ps;                            // per-lane partial (cross-quad later)
    asm volatile("s_waitcnt lgkmcnt(0)" ::: "memory");
    __builtin_amdgcn_sched_barrier(0);
    // ---- PV from LDS (A = P rows q=l16; B = V^T rows d) — unchanged layout
    const short* Vc = &Vs[cur][0];
    __builtin_amdgcn_s_setprio(1);
    #pragma unroll
    for (int st=0; st<2; st++){
      s8v pa = ld8(&Pw[l16*72 + st*32 + quad*8]);
      #pragma unroll
      for (int tt=0; tt<16; tt++){
        int d = tt*16 + l16;
        s8v vb = ld8(Vc + d*64 + (((st*4 + quad) ^ (d & 7)) << 3));
        O[tt] = MFMA_BF16(pa, vb, O[tt]);
      }
    }
    __builtin_amdgcn_s_setprio(0);
    __syncthreads();   // drains vmcnt (prefetch done) + lgkm; flip safe
    cur ^= 1;
  }
  // ---- deferred cross-quad sum reduce + per-row broadcast (once)
  float s = lsum;
  s += __shfl_xor(s, 16);
  s += __shfl_xor(s, 32);
  float dnr[4];
  #pragma unroll
  for (int r=0;r<4;r++) dnr[r] = fmaxf(__shfl(s, quad*4 + r), 1e-30f);
  #pragma unroll
  for (int t=0;t<16;t++){
    #pragma unroll
    for (int r=0;r<4;r++){
      int row = qbase + quad*4 + r;
      int col = t*16 + l16;
      H[((size_t)b*Gdim + row)*Ddim + col] = f2bf(O[t][r] / dnr[r]);
    }
  }
}

// ------------------------------------------------------------ mean + output
__global__ __launch_bounds__(256) void mean_partial(const float* __restrict__ h32,
                                                    float* __restrict__ part){
  int b = blockIdx.x, c = blockIdx.y, d = threadIdx.x;
  float s = 0.f;
  for (int g = c*64; g < c*64 + 64; g++)
    s += h32[((size_t)b*Gdim + g)*Ddim + d];
  part[(b*16 + c)*Ddim + d] = s;
}
__global__ __launch_bounds__(256) void mean_final_dyn(const float* __restrict__ part,
                                                      void* __restrict__ out,
                                                      const int* __restrict__ flag){
  int i = blockIdx.x*256 + threadIdx.x;
  int b = i >> 8, d = i & 255;
  float s = 0.f;
  #pragma unroll
  for (int c=0;c<16;c++) s += part[(b*16 + c)*Ddim + d];
  s *= (1.f/1024.f);
  if (flag[0]) ((float*)out)[16777216 + i] = s;
  else         ((short*)out)[16777216 + i] = f2bf(s);
}
__global__ __launch_bounds__(256) void store_h(const float* __restrict__ h32,
                                               void* __restrict__ out,
                                               const int* __restrict__ flag){
  size_t i = (size_t)blockIdx.x*256 + threadIdx.x;
  if (flag[0]) ((float*)out)[i] = h32[i];
  else         ((short*)out)[i] = f2bf(h32[i]);
}

// ------------------------------------------------------------ launch
extern "C" void kernel_launch(void* const* d_in, const int* in_sizes, int n_in,
                              void* d_out, int out_size, void* d_ws, size_t ws_size,
                              hipStream_t stream)
{
  const void* xs  = d_in[0];
  const int*  mask= (const int*)d_in[1];
  const void* Wq  = d_in[2];
  const void* Wk  = d_in[3];
  const void* Wv  = d_in[4];
  const void* Wo  = d_in[5];
  const void* bo  = d_in[6];
  const void* Wf1 = d_in[7];
  const void* bf1 = d_in[8];
  const void* Wf2 = d_in[9];
  const void* bf2 = d_in[10];

  // weights: Wqkv(768K) + Wo(256K) + Wf1(1M) + Wf2(1M) + biasf(12K)
  const size_t W_ALL = 786432 + 262144 + 1048576 + 1048576 + 12288;  // 3,158,016
  const size_t BASE  = 256 + 67108864;                               // flag + h32
  int CB;
  if      (ws_size >= BASE + 134217728ull + W_ALL) CB = 64;   // 204.5 MB
  else if (ws_size >= BASE +  67108864ull + W_ALL) CB = 32;   // 137.4 MB (proven reachable)
  else if (ws_size >= BASE +  33554432ull + W_ALL) CB = 16;
  else CB = 0;

  char* p = (char*)d_ws;
  int* flag = (int*)p; p += 256;
  detect_dtype<<<1, 256, 0, stream>>>((const unsigned*)xs, flag);
  if (CB == 0){
    diag_ws<<<1, 64, 0, stream>>>(d_out, 2000.f + (float)(ws_size >> 20), flag);
    return;
  }
  const int M = CB * 1024, nch = 64 / CB;
  float* h32 = (float*)p; p += 67108864;
  char* arena = p;        p += (size_t)CB * 2097152;
  short* WqkvT = (short*)p; p += 786432;
  short* WoT   = (short*)p; p += 262144;
  short* Wf1T  = (short*)p; p += 1048576;
  short* Wf2T  = (short*)p; p += 1048576;
  float* biasf = (float*)p; p += 12288;
  float* part  = (float*)arena;          // arena dead by mean time

  short* Qc  = (short*)arena;
  short* Kc  = Qc + (size_t)M*256;
  short* Vtc = Qc + (size_t)2*M*256;
  short* Hc  = Qc + (size_t)3*M*256;
  short* Tc  = Qc;                       // FFN intermediate spans whole arena

  cast_in<<<8192, 256, 0, stream>>>(xs, h32, flag);
  dim3 tb(32,8);
  transpose_w<<<dim3(8,8,2),  tb, 0, stream>>>(Wq,  WqkvT, 256, 256,  flag, 196608, 0);
  transpose_w<<<dim3(8,8,2),  tb, 0, stream>>>(Wk,  WqkvT, 256, 256,  flag, 196608, 65536);
  transpose_w<<<dim3(8,8,2),  tb, 0, stream>>>(Wv,  WqkvT, 256, 256,  flag, 196608, 131072);
  transpose_w<<<dim3(8,8,2),  tb, 0, stream>>>(Wo,  WoT,   256, 256,  flag, 65536, 0);
  transpose_w<<<dim3(32,8,2), tb, 0, stream>>>(Wf1, Wf1T,  256, 1024, flag, 262144, 0);
  transpose_w<<<dim3(8,32,2), tb, 0, stream>>>(Wf2, Wf2T,  1024, 256, flag, 262144, 0);
  bias_prep<<<12, 256, 0, stream>>>(bo, bf1, bf2, biasf, flag);

  for (int c=0; c<nch; c++){
    float* hc = h32 + (size_t)c*M*256;
    const int* mc = mask + (size_t)c*M;
    for (int l=0; l<2; l++){
      // fused QKV: A = h fp32 (hi), B = stacked [768][256]
      gemm_t<1,5><<<dim3(M/128,6), 256, 0, stream>>>(hc, WqkvT + l*196608, nullptr,
                                                     nullptr, Qc, 768, 256, 256, 256, M);
      flash_attn<<<dim3(8*CB), 512, 0, stream>>>(Qc, Kc, Vtc, mc, Hc);
      // O-proj: h32 += Hc*Wo + bo
      gemm_t<0,4><<<dim3(M/128,2), 256, 0, stream>>>(Hc, WoT + l*65536, biasf + l*256,
                                                     hc, nullptr, 256, 256, 256, 256, M);
      // FFN1: T = relu(h*Wf1 + b), A split
      gemm_t<2,1><<<dim3(M/128,8), 256, 0, stream>>>(hc, Wf1T + l*262144, biasf + 512 + l*1024,
                                                     nullptr, Tc, 1024, 256, 256, 256, M);
      // FFN2: h32 += T*Wf2 + b
      gemm_t<0,4><<<dim3(M/128,2), 256, 0, stream>>>(Tc, Wf2T + l*262144, biasf + 2560 + l*256,
                                                     hc, nullptr, 256, 1024, 1024, 1024, M);
    }
  }
  mean_partial<<<dim3(64,16), 256, 0, stream>>>(h32, part);
  store_h<<<65536, 256, 0, stream>>>(h32, d_out, flag);
  mean_final_dyn<<<64, 256, 0, stream>>>(part, d_out, flag);
}